// Round 2
// baseline (532.112 us; speedup 1.0000x reference)
//
#include <hip/hip_runtime.h>
#include <hip/hip_bf16.h>
#include <cstdint>

#define B_DIM 32
#define T_DIM 1000
#define D_DIM 768
#define V_DIM 31
#define L_DIM 200
#define S_DIM 401      // 2L+1 CTC states
#define SP 7           // states per lane (64*7 = 448 >= 401)
#define S_PAD 448
#define VSTRIDE 32     // padded log-prob row stride: 32 floats = 128 B
#define CH 4           // prefetch chunk (time steps)
#define NEGF (-1e30f)  // reference's log-domain 'zero'

// ---------------------------------------------------------------------------
// Kernel 1: logits = pred @ W^T + b, log_probs = log_softmax  -> ws (B,T,32)
// Block = 256 threads = 4 waves. Each wave owns one K-segment (192 of 768) for
// 64 rows (lane = row). W addresses are wave-uniform -> scalar loads.
// ---------------------------------------------------------------------------
__global__ __launch_bounds__(256) void head_logsm_kernel(
    const float* __restrict__ pred,
    const float* __restrict__ W,
    const float* __restrict__ bias,
    float* __restrict__ logp)
{
    __shared__ float part[4][64][V_DIM];      // per-seg partial dots
    __shared__ float lrow[64][V_DIM + 2];     // stride 33 -> no bank conflict
    const int tid  = threadIdx.x;
    const int lane = tid & 63;
    const int seg  = __builtin_amdgcn_readfirstlane(tid >> 6);
    const int row  = blockIdx.x * 64 + lane;  // grid = B*T/64 blocks exactly

    const float* pr = pred + (size_t)row * D_DIM + seg * 192;
    const float* wb = W + seg * 192;

    float acc[V_DIM];
#pragma unroll
    for (int v = 0; v < V_DIM; ++v) acc[v] = 0.f;

    for (int k = 0; k < 192; k += 4) {
        const float4 x = *reinterpret_cast<const float4*>(pr + k);
#pragma unroll
        for (int v = 0; v < V_DIM; ++v) {
            const float* wp = wb + v * D_DIM + k;   // wave-uniform -> s_load
            acc[v] = fmaf(x.x, wp[0], acc[v]);
            acc[v] = fmaf(x.y, wp[1], acc[v]);
            acc[v] = fmaf(x.z, wp[2], acc[v]);
            acc[v] = fmaf(x.w, wp[3], acc[v]);
        }
    }
#pragma unroll
    for (int v = 0; v < V_DIM; ++v) part[seg][lane][v] = acc[v];
    __syncthreads();

    for (int idx = tid; idx < 64 * V_DIM; idx += 256) {
        const int r = idx / V_DIM;
        const int v = idx - r * V_DIM;
        lrow[r][v] = part[0][r][v] + part[1][r][v] + part[2][r][v] + part[3][r][v] + bias[v];
    }
    __syncthreads();

    if (tid < 64) {
        const int r = tid;
        float m = lrow[r][0];
#pragma unroll
        for (int v = 1; v < V_DIM; ++v) m = fmaxf(m, lrow[r][v]);
        float s = 0.f;
#pragma unroll
        for (int v = 0; v < V_DIM; ++v) s += __expf(lrow[r][v] - m);
        const float ls = __logf(s);
        float* op = logp + (size_t)(blockIdx.x * 64 + r) * VSTRIDE;
#pragma unroll
        for (int v = 0; v < V_DIM; ++v) op[v] = lrow[r][v] - m - ls;
        op[V_DIM] = NEGF;  // deterministic pad (never gathered: eoff <= 30)
    }
}

// ---------------------------------------------------------------------------
// Kernel 2: CTC forward recursion in LOG domain — arithmetic-exact port of the
// reference scan. One wave per batch, 7 states/lane, neighbors via shfl_up,
// log-prob rows prefetched double-buffered (row = 1 cache line).
// ---------------------------------------------------------------------------
__global__ __launch_bounds__(64, 1) void ctc_alpha_kernel(
    const float* __restrict__ logp,
    const int* __restrict__ targets,
    const int* __restrict__ in_lens,
    const int* __restrict__ tgt_lens,
    float* __restrict__ out_nll)
{
    const int b    = blockIdx.x;
    const int lane = threadIdx.x;
    const int Tin  = in_lens[b];
    const int tl   = tgt_lens[b];
    const int* tgt = targets + b * L_DIM;
    const float* __restrict__ prow = logp + (size_t)b * T_DIM * VSTRIDE;

    // Per-state constants. ext[2k]=blank(0), ext[2k+1]=tgt[k];
    // skip iff s odd, s>=3, tgt[k]!=tgt[k-1]. States 401..447 = padding
    // (blank dynamics, init NEG, never read out).
    int  eoff[SP];
    bool msk[SP];
#pragma unroll
    for (int i = 0; i < SP; ++i) {
        const int s = lane * SP + i;
        int e = 0;
        bool mm = false;
        if (s < S_DIM && (s & 1)) {
            const int k = (s - 1) >> 1;
            const int lab = tgt[k];
            e = lab;
            if (s >= 3 && lab != tgt[k - 1]) mm = true;
        }
        eoff[i] = e;
        msk[i]  = mm;
    }

    // log-alpha at t=0
    float a[SP];
#pragma unroll
    for (int i = 0; i < SP; ++i) a[i] = NEGF;
    if (lane == 0) {
        a[0] = prow[0];
        a[1] = prow[eoff[1]];
    }

    float pA[CH][SP], pB[CH][SP];

    auto LOAD = [&](float (&pb)[CH][SP], int tbase) {
#pragma unroll
        for (int j = 0; j < CH; ++j) {
            int t = tbase + j;
            if (t > T_DIM - 1) t = T_DIM - 1;   // clamp; values unused past Tin
            const float* r = prow + (size_t)t * VSTRIDE;
#pragma unroll
            for (int i = 0; i < SP; ++i) pb[j][i] = r[eoff[i]];
        }
    };

    // Exact reference formula: m=max3; new = m + log(e^(x0-m)+e^(x1-m)+e^(x2-m)).
    // All-NEG case: m=NEG, s=3, result NEG+log3 — same as reference.
    auto lse3 = [](float x0, float x1, float x2) {
        const float m = fmaxf(fmaxf(x0, x1), x2);
        const float s = __expf(x0 - m) + __expf(x1 - m) + __expf(x2 - m);
        return m + __logf(s);
    };

    auto STEP = [&](const float (&pp)[SP], int t) {
        if (t >= Tin) return;                    // wave-uniform freeze
        float am1 = __shfl_up(a[SP - 1], 1);     // state s-1 from prev lane
        float am2 = __shfl_up(a[SP - 2], 1);     // state s-2 from prev lane
        if (lane == 0) { am1 = NEGF; am2 = NEGF; }
        float nw[SP];
        nw[0] = lse3(a[0], am1,  msk[0] ? am2  : NEGF) + pp[0];
        nw[1] = lse3(a[1], a[0], msk[1] ? am1  : NEGF) + pp[1];
#pragma unroll
        for (int i = 2; i < SP; ++i)
            nw[i] = lse3(a[i], a[i - 1], msk[i] ? a[i - 2] : NEGF) + pp[i];
#pragma unroll
        for (int i = 0; i < SP; ++i) a[i] = nw[i];
    };

    LOAD(pA, 1);
    int tb = 1;
    for (;;) {
        LOAD(pB, tb + CH);
#pragma unroll
        for (int j = 0; j < CH; ++j) STEP(pA[j], tb + j);
        tb += CH;
        if (tb >= Tin) break;
        LOAD(pA, tb + CH);
#pragma unroll
        for (int j = 0; j < CH; ++j) STEP(pB[j], tb + j);
        tb += CH;
        if (tb >= Tin) break;
    }

    // gather final states 2tl-1, 2tl
    __shared__ float sal[S_PAD];
#pragma unroll
    for (int i = 0; i < SP; ++i) sal[lane * SP + i] = a[i];
    __syncthreads();
    if (lane == 0) {
        const float a0 = sal[2 * tl - 1];
        const float a1 = sal[2 * tl];
        const float m  = fmaxf(a0, a1);
        float nll = -(m + __logf(__expf(a0 - m) + __expf(a1 - m)));
        if (!(nll < 1e29f)) nll = 0.f;           // zero_infinity (inf/NaN too)
        out_nll[b] = nll / (float)tl;
    }
}

// ---------------------------------------------------------------------------
// Kernel 3: deterministic mean over B (no float atomics -> bitwise stable)
// ---------------------------------------------------------------------------
__global__ void finalize_kernel(const float* __restrict__ nll, float* __restrict__ out)
{
    if (threadIdx.x == 0 && blockIdx.x == 0) {
        float s = 0.f;
        for (int i = 0; i < B_DIM; ++i) s += nll[i];
        out[0] = s * (1.0f / (float)B_DIM);
    }
}

extern "C" void kernel_launch(void* const* d_in, const int* in_sizes, int n_in,
                              void* d_out, int out_size, void* d_ws, size_t ws_size,
                              hipStream_t stream)
{
    const float* pred     = (const float*)d_in[0];
    const int*   targets  = (const int*)d_in[1];
    const int*   in_lens  = (const int*)d_in[2];
    const int*   tgt_lens = (const int*)d_in[3];
    const float* W        = (const float*)d_in[4];
    const float* bias     = (const float*)d_in[5];

    float* logp = (float*)d_ws;                                   // 32*1000*32 f32 = 4.1 MB
    float* nll  = logp + (size_t)B_DIM * T_DIM * VSTRIDE;         // 32 f32
    float* out  = (float*)d_out;

    head_logsm_kernel<<<(B_DIM * T_DIM) / 64, 256, 0, stream>>>(pred, W, bias, logp);
    ctc_alpha_kernel<<<B_DIM, 64, 0, stream>>>(logp, targets, in_lens, tgt_lens, nll);
    finalize_kernel<<<1, 64, 0, stream>>>(nll, out);
}

// Round 3
// 244.664 us; speedup vs baseline: 2.1749x; 2.1749x over previous
//
#include <hip/hip_runtime.h>
#include <hip/hip_bf16.h>
#include <cstdint>
#include <math.h>

#define B_DIM 32
#define T_DIM 1000
#define D_DIM 768
#define V_DIM 31
#define L_DIM 200
#define S_DIM 401      // 2L+1 CTC states
#define SP 7           // states per lane (64*7 = 448 >= 401)
#define S_PAD 448
#define VSTRIDE 32     // padded prob-row stride: 32 floats = 128 B = 1 cache line
#define CH 8           // prefetch chunk (time steps)

// ---------------------------------------------------------------------------
// Kernel 1: logits = pred @ W^T + b, probs = softmax  -> ws (B,T,32), linear.
// (Round-2 structure, verified correct; only the output domain changed.)
// ---------------------------------------------------------------------------
__global__ __launch_bounds__(256) void head_softmax_kernel(
    const float* __restrict__ pred,
    const float* __restrict__ W,
    const float* __restrict__ bias,
    float* __restrict__ probs)
{
    __shared__ float part[4][64][V_DIM];
    __shared__ float lrow[64][V_DIM + 2];
    const int tid  = threadIdx.x;
    const int lane = tid & 63;
    const int seg  = __builtin_amdgcn_readfirstlane(tid >> 6);
    const int row  = blockIdx.x * 64 + lane;

    const float* pr = pred + (size_t)row * D_DIM + seg * 192;
    const float* wb = W + seg * 192;

    float acc[V_DIM];
#pragma unroll
    for (int v = 0; v < V_DIM; ++v) acc[v] = 0.f;

    for (int k = 0; k < 192; k += 4) {
        const float4 x = *reinterpret_cast<const float4*>(pr + k);
#pragma unroll
        for (int v = 0; v < V_DIM; ++v) {
            const float* wp = wb + v * D_DIM + k;   // wave-uniform -> s_load
            acc[v] = fmaf(x.x, wp[0], acc[v]);
            acc[v] = fmaf(x.y, wp[1], acc[v]);
            acc[v] = fmaf(x.z, wp[2], acc[v]);
            acc[v] = fmaf(x.w, wp[3], acc[v]);
        }
    }
#pragma unroll
    for (int v = 0; v < V_DIM; ++v) part[seg][lane][v] = acc[v];
    __syncthreads();

    for (int idx = tid; idx < 64 * V_DIM; idx += 256) {
        const int r = idx / V_DIM;
        const int v = idx - r * V_DIM;
        lrow[r][v] = part[0][r][v] + part[1][r][v] + part[2][r][v] + part[3][r][v] + bias[v];
    }
    __syncthreads();

    if (tid < 64) {
        const int r = tid;
        float m = lrow[r][0];
#pragma unroll
        for (int v = 1; v < V_DIM; ++v) m = fmaxf(m, lrow[r][v]);
        float e[V_DIM];
        float s = 0.f;
#pragma unroll
        for (int v = 0; v < V_DIM; ++v) { e[v] = __expf(lrow[r][v] - m); s += e[v]; }
        const float inv = 1.0f / s;
        float* op = probs + (size_t)(blockIdx.x * 64 + r) * VSTRIDE;
#pragma unroll
        for (int v = 0; v < V_DIM; ++v) op[v] = e[v] * inv;
        op[V_DIM] = 0.f;
    }
}

// ---------------------------------------------------------------------------
// Kernel 2: CTC forward recursion, linear domain, per-lane pow2 scaling.
// One wave per batch. Each lane: 7 alphas renormalized to [0.5,1) max + int
// z2 (log2 scale). No transcendentals in the loop (frexp/ldexp only, exact).
// Empty lanes adopt neighbor z2 so the reachability frontier crosses lane
// boundaries at the correct absolute scale.
// ---------------------------------------------------------------------------
__global__ __launch_bounds__(64, 1) void ctc_alpha_kernel(
    const float* __restrict__ probs,
    const int* __restrict__ targets,
    const int* __restrict__ in_lens,
    const int* __restrict__ tgt_lens,
    float* __restrict__ out_nll)
{
    const int b    = blockIdx.x;
    const int lane = threadIdx.x;
    const int Tin  = in_lens[b];
    const int tl   = tgt_lens[b];
    const int* tgt = targets + b * L_DIM;
    const float* __restrict__ prow = probs + (size_t)b * T_DIM * VSTRIDE;

    // Per-state constants: ext label offset + skip mask (as float 0/1).
    int   eoff[SP];
    float m2[SP];
#pragma unroll
    for (int i = 0; i < SP; ++i) {
        const int s = lane * SP + i;
        int e = 0;
        float mm = 0.f;
        if (s < S_DIM && (s & 1)) {
            const int k = (s - 1) >> 1;
            const int lab = tgt[k];
            e = lab;
            if (s >= 3 && lab != tgt[k - 1]) mm = 1.f;
        }
        eoff[i] = e;
        m2[i]   = mm;
    }

    // t=0 init: linear probs, z2 = 0 everywhere.
    float a[SP];
#pragma unroll
    for (int i = 0; i < SP; ++i) a[i] = 0.f;
    if (lane == 0) {
        a[0] = prow[0];
        a[1] = prow[eoff[1]];
    }
    int z2 = 0;

    float pA[CH][SP], pB[CH][SP];

    auto LOAD = [&](float (&pb)[CH][SP], int tbase) {
#pragma unroll
        for (int j = 0; j < CH; ++j) {
            int t = tbase + j;
            if (t > T_DIM - 1) t = T_DIM - 1;   // clamp; values unused past Tin
            const float* r = prow + (size_t)t * VSTRIDE;
#pragma unroll
            for (int i = 0; i < SP; ++i) pb[j][i] = r[eoff[i]];
        }
    };

    auto STEP = [&](const float (&pp)[SP], int t) {
        if (t >= Tin) return;                    // wave-uniform freeze
        const float a6 = __shfl_up(a[SP - 1], 1);
        const float a5 = __shfl_up(a[SP - 2], 1);
        const int   zp = __shfl_up(z2, 1);
        int dz = zp - z2;
        if (dz > 126) dz = 126;                  // safety clamp vs inf
        const float f = ldexpf(1.0f, dz);        // exact pow2 rescale
        float am1, am2;
        if (lane == 0) { am1 = 0.f; am2 = 0.f; }
        else           { am1 = a6 * f; am2 = a5 * f; }
        float nw[SP];
        nw[0] = (a[0] + am1  + m2[0] * am2) * pp[0];
        nw[1] = (a[1] + a[0] + m2[1] * am1) * pp[1];
#pragma unroll
        for (int i = 2; i < SP; ++i)
            nw[i] = (a[i] + a[i - 1] + m2[i] * a[i - 2]) * pp[i];
        // per-lane renorm to [0.5,1) via exponent extraction (exact)
        const float mx = fmaxf(fmaxf(fmaxf(nw[0], nw[1]), fmaxf(nw[2], nw[3])),
                               fmaxf(fmaxf(nw[4], nw[5]), nw[6]));
        int e;
        (void)frexpf(mx, &e);                    // frexpf(0,&e) -> e = 0
        z2 = (mx > 0.f) ? (z2 + e) : zp;         // empty lane adopts neighbor scale
#pragma unroll
        for (int i = 0; i < SP; ++i) a[i] = ldexpf(nw[i], -e);
    };

    LOAD(pA, 1);
    int tb = 1;
    for (;;) {
        LOAD(pB, tb + CH);
#pragma unroll
        for (int j = 0; j < CH; ++j) STEP(pA[j], tb + j);
        tb += CH;
        if (tb >= Tin) break;
        LOAD(pA, tb + CH);
#pragma unroll
        for (int j = 0; j < CH; ++j) STEP(pB[j], tb + j);
        tb += CH;
        if (tb >= Tin) break;
    }

    // absolute log-alpha to LDS: log(a) + z2*ln2  (7 logs per lane, once)
    __shared__ float sal[S_PAD];
    const float zln2 = (float)z2 * 0.69314718055994530942f;
#pragma unroll
    for (int i = 0; i < SP; ++i) sal[lane * SP + i] = __logf(a[i]) + zln2;
    __syncthreads();
    if (lane == 0) {
        const float a0 = sal[2 * tl - 1];
        const float a1 = sal[2 * tl];
        const float m  = fmaxf(a0, a1);
        float nll = -(m + __logf(__expf(a0 - m) + __expf(a1 - m)));
        if (!(nll < 1e29f)) nll = 0.f;           // zero_infinity (inf/NaN too)
        out_nll[b] = nll / (float)tl;
    }
}

// ---------------------------------------------------------------------------
// Kernel 3: deterministic mean over B
// ---------------------------------------------------------------------------
__global__ void finalize_kernel(const float* __restrict__ nll, float* __restrict__ out)
{
    if (threadIdx.x == 0 && blockIdx.x == 0) {
        float s = 0.f;
        for (int i = 0; i < B_DIM; ++i) s += nll[i];
        out[0] = s * (1.0f / (float)B_DIM);
    }
}

extern "C" void kernel_launch(void* const* d_in, const int* in_sizes, int n_in,
                              void* d_out, int out_size, void* d_ws, size_t ws_size,
                              hipStream_t stream)
{
    const float* pred     = (const float*)d_in[0];
    const int*   targets  = (const int*)d_in[1];
    const int*   in_lens  = (const int*)d_in[2];
    const int*   tgt_lens = (const int*)d_in[3];
    const float* W        = (const float*)d_in[4];
    const float* bias     = (const float*)d_in[5];

    float* probs = (float*)d_ws;                                  // 32*1000*32 f32 = 4.1 MB
    float* nll   = probs + (size_t)B_DIM * T_DIM * VSTRIDE;       // 32 f32
    float* out   = (float*)d_out;

    head_softmax_kernel<<<(B_DIM * T_DIM) / 64, 256, 0, stream>>>(pred, W, bias, probs);
    ctc_alpha_kernel<<<B_DIM, 64, 0, stream>>>(probs, targets, in_lens, tgt_lens, nll);
    finalize_kernel<<<1, 64, 0, stream>>>(nll, out);
}

// Round 4
// 242.866 us; speedup vs baseline: 2.1910x; 1.0074x over previous
//
#include <hip/hip_runtime.h>
#include <hip/hip_bf16.h>
#include <cstdint>
#include <math.h>

#define B_DIM 32
#define T_DIM 1000
#define D_DIM 768
#define V_DIM 31
#define L_DIM 200
#define S_DIM 401      // 2L+1 CTC states
#define SP 7           // states per lane (64*7 = 448 >= 401)
#define S_PAD 448
#define VSTRIDE 32     // padded prob-row stride: 32 floats = 128 B = 1 cache line
#define CH 4           // chunk = renorm period (steps)

// ---------------------------------------------------------------------------
// Kernel 1: logits = pred @ W^T + b, probs = softmax -> ws (B,T,32), linear.
// 2 rows per lane (128 rows/block) to amortize wave-uniform W scalar loads.
// ---------------------------------------------------------------------------
__global__ __launch_bounds__(256) void head_softmax_kernel(
    const float* __restrict__ pred,
    const float* __restrict__ W,
    const float* __restrict__ bias,
    float* __restrict__ probs)
{
    __shared__ float part[4][128][V_DIM];     // 63.5 KB
    const int tid  = threadIdx.x;
    const int lane = tid & 63;
    const int seg  = __builtin_amdgcn_readfirstlane(tid >> 6);
    const int rbase = blockIdx.x * 128;       // grid = B*T/128 = 250 exactly

    const float* p0 = pred + (size_t)(rbase + lane) * D_DIM + seg * 192;
    const float* p1 = p0 + (size_t)64 * D_DIM;
    const float* wb = W + seg * 192;

    float acc0[V_DIM], acc1[V_DIM];
#pragma unroll
    for (int v = 0; v < V_DIM; ++v) { acc0[v] = 0.f; acc1[v] = 0.f; }

    for (int k = 0; k < 192; k += 4) {
        const float4 x0 = *reinterpret_cast<const float4*>(p0 + k);
        const float4 x1 = *reinterpret_cast<const float4*>(p1 + k);
#pragma unroll
        for (int v = 0; v < V_DIM; ++v) {
            const float* wp = wb + v * D_DIM + k;   // wave-uniform -> s_load
            const float w0 = wp[0], w1 = wp[1], w2 = wp[2], w3 = wp[3];
            acc0[v] = fmaf(x0.x, w0, acc0[v]);
            acc0[v] = fmaf(x0.y, w1, acc0[v]);
            acc0[v] = fmaf(x0.z, w2, acc0[v]);
            acc0[v] = fmaf(x0.w, w3, acc0[v]);
            acc1[v] = fmaf(x1.x, w0, acc1[v]);
            acc1[v] = fmaf(x1.y, w1, acc1[v]);
            acc1[v] = fmaf(x1.z, w2, acc1[v]);
            acc1[v] = fmaf(x1.w, w3, acc1[v]);
        }
    }
#pragma unroll
    for (int v = 0; v < V_DIM; ++v) {
        part[seg][lane][v]      = acc0[v];
        part[seg][lane + 64][v] = acc1[v];
    }
    __syncthreads();

    if (tid < 128) {
        const int r = tid;
        float lg[V_DIM];
        float m = -1e30f;
#pragma unroll
        for (int v = 0; v < V_DIM; ++v) {
            lg[v] = part[0][r][v] + part[1][r][v] + part[2][r][v] + part[3][r][v] + bias[v];
            m = fmaxf(m, lg[v]);
        }
        float e[V_DIM];
        float s = 0.f;
#pragma unroll
        for (int v = 0; v < V_DIM; ++v) { e[v] = __expf(lg[v] - m); s += e[v]; }
        const float inv = 1.0f / s;
        float* op = probs + (size_t)(rbase + r) * VSTRIDE;
#pragma unroll
        for (int v = 0; v < V_DIM; ++v) op[v] = e[v] * inv;
        op[V_DIM] = 0.f;
    }
}

// ---------------------------------------------------------------------------
// Kernel 2: CTC forward recursion, linear domain, per-lane pow2 scaling with
// renorm every CH=4 steps. Between renorms the neighbor scale factor f is
// constant, so the inner step is just 2 shuffles + ~25 VALU ops.
// All pow2 ops are exact -> results bit-identical to per-step renorm.
// ---------------------------------------------------------------------------
__global__ __launch_bounds__(64, 1) void ctc_alpha_kernel(
    const float* __restrict__ probs,
    const int* __restrict__ targets,
    const int* __restrict__ in_lens,
    const int* __restrict__ tgt_lens,
    float* __restrict__ out_nll)
{
    const int b    = blockIdx.x;
    const int lane = threadIdx.x;
    const int Tin  = in_lens[b];
    const int tl   = tgt_lens[b];
    const int* tgt = targets + b * L_DIM;
    const float* __restrict__ prow = probs + (size_t)b * T_DIM * VSTRIDE;

    int   eoff[SP];
    float m2[SP];
#pragma unroll
    for (int i = 0; i < SP; ++i) {
        const int s = lane * SP + i;
        int e = 0;
        float mm = 0.f;
        if (s < S_DIM && (s & 1)) {
            const int k = (s - 1) >> 1;
            const int lab = tgt[k];
            e = lab;
            if (s >= 3 && lab != tgt[k - 1]) mm = 1.f;
        }
        eoff[i] = e;
        m2[i]   = mm;
    }

    // t=0 init
    float a[SP];
#pragma unroll
    for (int i = 0; i < SP; ++i) a[i] = 0.f;
    if (lane == 0) {
        a[0] = prow[0];
        a[1] = prow[eoff[1]];
    }
    int   z2 = 0;
    float f  = (lane == 0) ? 0.f : 1.0f;   // neighbor scale; 0 kills lane-0 inflow

    float pA[CH][SP], pB[CH][SP];

    auto LOAD = [&](float (&pb)[CH][SP], int tbase) {
#pragma unroll
        for (int j = 0; j < CH; ++j) {
            int t = tbase + j;
            if (t > T_DIM - 1) t = T_DIM - 1;   // clamp; values unused past Tin
            const float* r = prow + (size_t)t * VSTRIDE;
#pragma unroll
            for (int i = 0; i < SP; ++i) pb[j][i] = r[eoff[i]];
        }
    };

    auto STEP = [&](const float (&pp)[SP]) {
        const float a6  = __shfl_up(a[SP - 1], 1);
        const float a5  = __shfl_up(a[SP - 2], 1);
        const float am1 = a6 * f;               // f==0 on lane 0
        const float am2 = a5 * f;
        float nw[SP];
        nw[0] = (a[0] + am1  + m2[0] * am2) * pp[0];
        nw[1] = (a[1] + a[0] + m2[1] * am1) * pp[1];
#pragma unroll
        for (int i = 2; i < SP; ++i)
            nw[i] = (a[i] + a[i - 1] + m2[i] * a[i - 2]) * pp[i];
#pragma unroll
        for (int i = 0; i < SP; ++i) a[i] = nw[i];
    };

    auto RENORM = [&]() {
        const float mx = fmaxf(fmaxf(fmaxf(a[0], a[1]), fmaxf(a[2], a[3])),
                               fmaxf(fmaxf(a[4], a[5]), a[6]));
        int e;
        (void)frexpf(mx, &e);                    // mx==0 -> e=0
        const int zc = z2 + e;                   // candidate (== z2 when empty)
        const int zp = __shfl_up(zc, 1);         // neighbor candidate
        z2 = (mx > 0.f) ? zc : ((lane == 0) ? zc : zp);  // empty lanes adopt
#pragma unroll
        for (int i = 0; i < SP; ++i) a[i] = ldexpf(a[i], -e);
        int dz = zp - z2;                        // exact when neighbor live;
        if (dz > 126) dz = 126;                  // irrelevant (x0) otherwise
        if (dz < -126) dz = -126;
        f = (lane == 0) ? 0.f : ldexpf(1.0f, dz);
    };

    LOAD(pA, 1);
    int tb = 1;
    int cur = 0;
    while (tb + CH <= Tin) {
        if (cur == 0) {
            LOAD(pB, tb + CH);
            STEP(pA[0]); STEP(pA[1]); STEP(pA[2]); STEP(pA[3]);
        } else {
            LOAD(pA, tb + CH);
            STEP(pB[0]); STEP(pB[1]); STEP(pB[2]); STEP(pB[3]);
        }
        RENORM();
        tb += CH;
        cur ^= 1;
    }
    // tail: rem <= 3 steps, statically unrolled (no runtime array indexing)
    const int rem = Tin - tb;
    if (cur == 0) {
        if (rem > 0) STEP(pA[0]);
        if (rem > 1) STEP(pA[1]);
        if (rem > 2) STEP(pA[2]);
    } else {
        if (rem > 0) STEP(pB[0]);
        if (rem > 1) STEP(pB[1]);
        if (rem > 2) STEP(pB[2]);
    }

    // absolute log-alpha: log(a) + z2*ln2
    __shared__ float sal[S_PAD];
    const float zln2 = (float)z2 * 0.69314718055994530942f;
#pragma unroll
    for (int i = 0; i < SP; ++i) sal[lane * SP + i] = __logf(a[i]) + zln2;
    __syncthreads();
    if (lane == 0) {
        const float a0 = sal[2 * tl - 1];
        const float a1 = sal[2 * tl];
        const float m  = fmaxf(a0, a1);
        float nll = -(m + __logf(__expf(a0 - m) + __expf(a1 - m)));
        if (!(nll < 1e29f)) nll = 0.f;           // zero_infinity (inf/NaN too)
        out_nll[b] = nll / (float)tl;
    }
}

// ---------------------------------------------------------------------------
// Kernel 3: deterministic mean over B
// ---------------------------------------------------------------------------
__global__ void finalize_kernel(const float* __restrict__ nll, float* __restrict__ out)
{
    if (threadIdx.x == 0 && blockIdx.x == 0) {
        float s = 0.f;
        for (int i = 0; i < B_DIM; ++i) s += nll[i];
        out[0] = s * (1.0f / (float)B_DIM);
    }
}

extern "C" void kernel_launch(void* const* d_in, const int* in_sizes, int n_in,
                              void* d_out, int out_size, void* d_ws, size_t ws_size,
                              hipStream_t stream)
{
    const float* pred     = (const float*)d_in[0];
    const int*   targets  = (const int*)d_in[1];
    const int*   in_lens  = (const int*)d_in[2];
    const int*   tgt_lens = (const int*)d_in[3];
    const float* W        = (const float*)d_in[4];
    const float* bias     = (const float*)d_in[5];

    float* probs = (float*)d_ws;                                  // 32*1000*32 f32 = 4.1 MB
    float* nll   = probs + (size_t)B_DIM * T_DIM * VSTRIDE;       // 32 f32
    float* out   = (float*)d_out;

    head_softmax_kernel<<<(B_DIM * T_DIM) / 128, 256, 0, stream>>>(pred, W, bias, probs);
    ctc_alpha_kernel<<<B_DIM, 64, 0, stream>>>(probs, targets, in_lens, tgt_lens, nll);
    finalize_kernel<<<1, 64, 0, stream>>>(nll, out);
}

// Round 5
// 222.014 us; speedup vs baseline: 2.3967x; 1.0939x over previous
//
#include <hip/hip_runtime.h>
#include <hip/hip_bf16.h>
#include <cstdint>
#include <math.h>

#define B_DIM 32
#define T_DIM 1000
#define D_DIM 768
#define V_DIM 31
#define L_DIM 200
#define S_DIM 401      // 2L+1 CTC states
#define SP 7           // states per lane (64*7 = 448 >= 401)
#define S_PAD 448
#define VSTRIDE 32     // padded prob-row stride: 32 floats = 128 B = 1 cache line
#define CH 4           // load chunk (steps); renorm every 2 steps
#define KT 64          // head k-tile

// Wave-wide shift-up-by-1 via DPP WAVE_SHR1 (0x138): pure VALU (~4 cyc) vs
// ds_bpermute (~100 cyc). Lane 0 receives 0 (bound-ctrl zero-fill; old=0
// covers the other bound_ctrl convention too).
__device__ __forceinline__ float shup1_f(float x) {
    int r = __builtin_amdgcn_update_dpp(0, __float_as_int(x), 0x138, 0xF, 0xF, true);
    return __int_as_float(r);
}
__device__ __forceinline__ int shup1_i(int x) {
    return __builtin_amdgcn_update_dpp(0, x, 0x138, 0xF, 0xF, true);
}

// ---------------------------------------------------------------------------
// Kernel 1: logits = pred @ W^T + b, probs = softmax -> ws (B,T,32), linear.
// W staged per k-tile into LDS (broadcast ds_read) -> no scalar-cache thrash.
// 1 row/lane, 4 waves = 4 k-segments of 192, 500 blocks (~2/CU).
// ---------------------------------------------------------------------------
__global__ __launch_bounds__(256) void head_softmax_kernel(
    const float* __restrict__ pred,
    const float* __restrict__ W,
    const float* __restrict__ bias,
    float* __restrict__ probs)
{
    __shared__ float smem[7936];   // Wl[4][31][KT] during compute; part[4][64][31] after
    const int tid  = threadIdx.x;
    const int lane = tid & 63;
    const int seg  = __builtin_amdgcn_readfirstlane(tid >> 6);
    const int row  = blockIdx.x * 64 + lane;   // grid = 32000/64 = 500 exactly

    const float* pr = pred + (size_t)row * D_DIM + seg * 192;

    float acc[V_DIM];
#pragma unroll
    for (int v = 0; v < V_DIM; ++v) acc[v] = 0.f;

    for (int kt = 0; kt < 192; kt += KT) {
        __syncthreads();
        // stage Wl[s][v][c] = W[v][s*192 + kt + c]; 7936 = 31 * 256 exactly
#pragma unroll
        for (int i = 0; i < 31; ++i) {
            const int idx = i * 256 + tid;
            const int s   = idx / 1984;          // 1984 = 31*KT
            const int r2  = idx - s * 1984;
            const int v   = r2 / KT;
            const int c   = r2 - v * KT;
            smem[idx] = W[v * D_DIM + s * 192 + kt + c];
        }
        __syncthreads();
        const float* wl = smem + seg * 1984;
        for (int k = 0; k < KT; k += 4) {
            const float4 x = *reinterpret_cast<const float4*>(pr + kt + k);
#pragma unroll
            for (int v = 0; v < V_DIM; ++v) {
                const float4 w4 = *reinterpret_cast<const float4*>(wl + v * KT + k);
                acc[v] = fmaf(x.x, w4.x, acc[v]);
                acc[v] = fmaf(x.y, w4.y, acc[v]);
                acc[v] = fmaf(x.z, w4.z, acc[v]);
                acc[v] = fmaf(x.w, w4.w, acc[v]);
            }
        }
    }

    __syncthreads();
    float* part = smem;                          // alias: [4][64][31]
#pragma unroll
    for (int v = 0; v < V_DIM; ++v) part[(seg * 64 + lane) * V_DIM + v] = acc[v];
    __syncthreads();

    if (tid < 64) {
        const int r = tid;
        float lg[V_DIM];
        float m = -1e30f;
#pragma unroll
        for (int v = 0; v < V_DIM; ++v) {
            lg[v] = part[r * V_DIM + v] + part[(64 + r) * V_DIM + v]
                  + part[(128 + r) * V_DIM + v] + part[(192 + r) * V_DIM + v] + bias[v];
            m = fmaxf(m, lg[v]);
        }
        float e[V_DIM];
        float s = 0.f;
#pragma unroll
        for (int v = 0; v < V_DIM; ++v) { e[v] = __expf(lg[v] - m); s += e[v]; }
        const float inv = 1.0f / s;
        float* op = probs + (size_t)(blockIdx.x * 64 + r) * VSTRIDE;
#pragma unroll
        for (int v = 0; v < V_DIM; ++v) op[v] = e[v] * inv;
        op[V_DIM] = 0.f;
    }
}

// ---------------------------------------------------------------------------
// Kernel 2: CTC forward recursion, linear domain, per-lane pow2 scaling.
// Neighbor exchange via DPP WAVE_SHR1 (VALU, not LDS). Renorm every 2 steps
// (pow2 ops exact). One wave per batch element.
// ---------------------------------------------------------------------------
__global__ __launch_bounds__(64, 1) void ctc_alpha_kernel(
    const float* __restrict__ probs,
    const int* __restrict__ targets,
    const int* __restrict__ in_lens,
    const int* __restrict__ tgt_lens,
    float* __restrict__ out_nll)
{
    const int b    = blockIdx.x;
    const int lane = threadIdx.x;
    const int Tin  = in_lens[b];
    const int tl   = tgt_lens[b];
    const int* tgt = targets + b * L_DIM;
    const float* __restrict__ prow = probs + (size_t)b * T_DIM * VSTRIDE;

    int   eoff[SP];
    float m2[SP];
#pragma unroll
    for (int i = 0; i < SP; ++i) {
        const int s = lane * SP + i;
        int e = 0;
        float mm = 0.f;
        if (s < S_DIM && (s & 1)) {
            const int k = (s - 1) >> 1;
            const int lab = tgt[k];
            e = lab;
            if (s >= 3 && lab != tgt[k - 1]) mm = 1.f;
        }
        eoff[i] = e;
        m2[i]   = mm;
    }

    // t=0 init
    float a[SP];
#pragma unroll
    for (int i = 0; i < SP; ++i) a[i] = 0.f;
    if (lane == 0) {
        a[0] = prow[0];
        a[1] = prow[eoff[1]];
    }
    int   z2 = 0;
    float f  = (lane == 0) ? 0.f : 1.0f;   // neighbor scale; 0 kills lane-0 inflow

    float pA[CH][SP], pB[CH][SP];

    auto LOAD = [&](float (&pb)[CH][SP], int tbase) {
#pragma unroll
        for (int j = 0; j < CH; ++j) {
            int t = tbase + j;
            if (t > T_DIM - 1) t = T_DIM - 1;   // clamp; values unused past Tin
            const float* r = prow + (size_t)t * VSTRIDE;
#pragma unroll
            for (int i = 0; i < SP; ++i) pb[j][i] = r[eoff[i]];
        }
    };

    auto STEP = [&](const float (&pp)[SP]) {
        const float a6  = shup1_f(a[SP - 1]);   // DPP: lane0 -> 0
        const float a5  = shup1_f(a[SP - 2]);
        const float am1 = a6 * f;
        const float am2 = a5 * f;
        float nw[SP];
        nw[0] = (a[0] + am1  + m2[0] * am2) * pp[0];
        nw[1] = (a[1] + a[0] + m2[1] * am1) * pp[1];
#pragma unroll
        for (int i = 2; i < SP; ++i)
            nw[i] = (a[i] + a[i - 1] + m2[i] * a[i - 2]) * pp[i];
#pragma unroll
        for (int i = 0; i < SP; ++i) a[i] = nw[i];
    };

    auto RENORM = [&]() {
        const float mx = fmaxf(fmaxf(fmaxf(a[0], a[1]), fmaxf(a[2], a[3])),
                               fmaxf(fmaxf(a[4], a[5]), a[6]));
        int e;
        (void)frexpf(mx, &e);                    // mx==0 -> e=0
        const int zc = z2 + e;                   // candidate (== z2 when empty)
        const int zp = shup1_i(zc);              // neighbor candidate (lane0 -> 0)
        z2 = (mx > 0.f) ? zc : ((lane == 0) ? zc : zp);  // empty lanes adopt
#pragma unroll
        for (int i = 0; i < SP; ++i) a[i] = ldexpf(a[i], -e);
        int dz = zp - z2;                        // exact when neighbor live
        if (dz > 126) dz = 126;
        if (dz < -126) dz = -126;
        f = (lane == 0) ? 0.f : ldexpf(1.0f, dz);
    };

    LOAD(pA, 1);
    int tb = 1;
    int cur = 0;
    while (tb + CH <= Tin) {
        if (cur == 0) {
            LOAD(pB, tb + CH);
            STEP(pA[0]); STEP(pA[1]); RENORM();
            STEP(pA[2]); STEP(pA[3]); RENORM();
        } else {
            LOAD(pA, tb + CH);
            STEP(pB[0]); STEP(pB[1]); RENORM();
            STEP(pB[2]); STEP(pB[3]); RENORM();
        }
        tb += CH;
        cur ^= 1;
    }
    // tail: rem <= 3 steps, statically unrolled
    const int rem = Tin - tb;
    if (cur == 0) {
        if (rem > 0) STEP(pA[0]);
        if (rem > 1) STEP(pA[1]);
        if (rem > 2) STEP(pA[2]);
    } else {
        if (rem > 0) STEP(pB[0]);
        if (rem > 1) STEP(pB[1]);
        if (rem > 2) STEP(pB[2]);
    }

    // absolute log-alpha: log(a) + z2*ln2
    __shared__ float sal[S_PAD];
    const float zln2 = (float)z2 * 0.69314718055994530942f;
#pragma unroll
    for (int i = 0; i < SP; ++i) sal[lane * SP + i] = __logf(a[i]) + zln2;
    __syncthreads();
    if (lane == 0) {
        const float a0 = sal[2 * tl - 1];
        const float a1 = sal[2 * tl];
        const float m  = fmaxf(a0, a1);
        float nll = -(m + __logf(__expf(a0 - m) + __expf(a1 - m)));
        if (!(nll < 1e29f)) nll = 0.f;           // zero_infinity (inf/NaN too)
        out_nll[b] = nll / (float)tl;
    }
}

// ---------------------------------------------------------------------------
// Kernel 3: deterministic mean over B
// ---------------------------------------------------------------------------
__global__ void finalize_kernel(const float* __restrict__ nll, float* __restrict__ out)
{
    if (threadIdx.x == 0 && blockIdx.x == 0) {
        float s = 0.f;
        for (int i = 0; i < B_DIM; ++i) s += nll[i];
        out[0] = s * (1.0f / (float)B_DIM);
    }
}

extern "C" void kernel_launch(void* const* d_in, const int* in_sizes, int n_in,
                              void* d_out, int out_size, void* d_ws, size_t ws_size,
                              hipStream_t stream)
{
    const float* pred     = (const float*)d_in[0];
    const int*   targets  = (const int*)d_in[1];
    const int*   in_lens  = (const int*)d_in[2];
    const int*   tgt_lens = (const int*)d_in[3];
    const float* W        = (const float*)d_in[4];
    const float* bias     = (const float*)d_in[5];

    float* probs = (float*)d_ws;                                  // 32*1000*32 f32 = 4.1 MB
    float* nll   = probs + (size_t)B_DIM * T_DIM * VSTRIDE;       // 32 f32
    float* out   = (float*)d_out;

    head_softmax_kernel<<<(B_DIM * T_DIM) / 64, 256, 0, stream>>>(pred, W, bias, probs);
    ctc_alpha_kernel<<<B_DIM, 64, 0, stream>>>(probs, targets, in_lens, tgt_lens, nll);
    finalize_kernel<<<1, 64, 0, stream>>>(nll, out);
}